// Round 18
// baseline (262.759 us; speedup 1.0000x reference)
//
#include <hip/hip_runtime.h>
#include <hip/hip_bf16.h>

// ---------------------------------------------------------------------------
// Attention_81449759801699 on MI355X (gfx950)
// R18 = R17 + gated fp32 bias table: if ws_size >= 196.1 MB, btab is stored
// fp32 (frag-tiled, after aws) and attn loads the QK C-init directly as
// f32x4 (deletes 8 unpack VALU/chunk). Otherwise identical bf16 path.
// ---------------------------------------------------------------------------

typedef unsigned short u16;
typedef unsigned int u32;
typedef float  f32x4  __attribute__((ext_vector_type(4)));
typedef float  fl4    __attribute__((ext_vector_type(4)));
typedef short  short8 __attribute__((ext_vector_type(8)));
typedef u32    u32x4  __attribute__((ext_vector_type(4)));
typedef u32    u32x2  __attribute__((ext_vector_type(2)));

#define EPSF 1e-5f
#define NH 8
#define NTP 416                        // 400 text tokens padded to 416 (13*32)
#define LOG2E 1.4426950408889634f
#define QSCALE (0.125f * LOG2E)
#define WS_BF32 196116480ull           // 182484992 + 8*16*13*2048*4

static __device__ __forceinline__ u16 f2bf(float f){
  u32 u = __builtin_bit_cast(u32, f);
  u += 0x7FFFu + ((u >> 16) & 1u);     // RNE (finite inputs only)
  return (u16)(u >> 16);
}
static __device__ __forceinline__ float u2f(u32 u){
  return __builtin_bit_cast(float, u);
}
static __device__ __forceinline__ u32 pk2bf(float lo, float hi){
  float2 f; f.x = lo; f.y = hi;
  __hip_bfloat162 b = __float22bfloat162_rn(f);
  u32 l = (u32)__bfloat16_as_ushort(b.x);
  u32 h = (u32)__bfloat16_as_ushort(b.y);
  return l | (h << 16);
}
static __device__ __forceinline__ f32x4 mfma16(short8 a, short8 b, f32x4 c){
  return __builtin_amdgcn_mfma_f32_16x16x32_bf16(a, b, c, 0, 0, 0);
}
static __device__ __forceinline__ void gld16(const void* g, void* l){
  __builtin_amdgcn_global_load_lds(
      (const __attribute__((address_space(1))) u32*)g,
      (__attribute__((address_space(3))) u32*)l, 16, 0, 0);
}

// ---------------------------------------------------------------------------
// Fused prep: flat grid, 256 thr.
//  [0,64):    wconv q_w;  [64,384): wconv kv_w;  [384,640): wconv p_w
//  [640,1664):   text -> bf16 padded
//  [1664,14976): bias table, OUTPUT-linear (coalesced writes), x log2e;
//                fp32 table when bf32 != 0, else bf16.
// ---------------------------------------------------------------------------
__device__ __forceinline__ void wconv_body(
    const float* __restrict__ w, const float* __restrict__ gamma,
    const float* __restrict__ var, u16* __restrict__ wT,
    int R, int C, int tx, int ty, int tid, u16* tile)
{
  #pragma unroll
  for (int i = 0; i < 16; ++i){
    int lin = tid + i*256;
    int rr = lin >> 6, cc = lin & 63;
    int c = tx*64 + cc;
    float s = gamma[c] * rsqrtf(var[c] + EPSF);
    tile[rr*65 + cc] = f2bf(w[(size_t)(ty*64 + rr)*C + c] * s);
  }
  __syncthreads();
  #pragma unroll
  for (int i = 0; i < 16; ++i){
    int lin = tid + i*256;
    int cc = lin >> 6, rr = lin & 63;
    wT[(size_t)(tx*64 + cc)*R + ty*64 + rr] = tile[rr*65 + cc];
  }
}

__global__ __launch_bounds__(256) void prep_kernel(
    const float* __restrict__ q_w, const float* __restrict__ q_g,
    const float* __restrict__ q_v, u16* __restrict__ qwT,
    const float* __restrict__ kv_w, const float* __restrict__ kv_g,
    const float* __restrict__ kv_v, u16* __restrict__ kvwT,
    const float* __restrict__ p_w, const float* __restrict__ p_g,
    const float* __restrict__ p_v, u16* __restrict__ pwT,
    const float* __restrict__ text, u16* __restrict__ textb,
    const float* __restrict__ ab, u16* __restrict__ btab,
    float* __restrict__ btabf, int bf32)
{
  __shared__ u16 tile[64*65];
  const int bk = blockIdx.x, tid = threadIdx.x;
  if (bk < 64){
    wconv_body(q_w, q_g, q_v, qwT, 512, 512, bk & 7, bk >> 3, tid, tile);
  } else if (bk < 384){
    int bb = bk - 64;
    wconv_body(kv_w, kv_g, kv_v, kvwT, 512, 2560, bb % 40, bb / 40, tid, tile);
  } else if (bk < 640){
    int bb = bk - 384;
    wconv_body(p_w, p_g, p_v, pwT, 2048, 512, bb & 7, bb >> 3, tid, tile);
  } else if (bk < 1664){
    int idx = (bk - 640)*256 + tid;       // 512*512
    int r = idx >> 9, c = idx & 511;
    float v = (r < 400) ? text[r*512 + c] : 0.f;
    textb[idx] = f2bf(v);
  } else {
    // bias, output-linear: o -> (h,n,t); writes fully coalesced
    int o = (bk - 1664)*256 + tid;        // 8*16*13*2048
    int tl  = o & 3;
    int nl  = (o >> 2) & 15;
    int lgq = (o >> 6) & 3;
    int tt  = (o >> 8) & 1;
    int w   = (o >> 9) & 3;
    int tile_ = o >> 11;
    int c   = tile_ % 13;
    int hq  = tile_ / 13;
    int qt  = hq & 15, h = hq >> 4;
    int t = c*32 + tt*16 + lgq*4 + tl;
    int n = qt*64 + w*16 + nl;
    float v;
    if (t >= 400) v = -1e30f;
    else {
      int i = n >> 5, j = n & 31;
      int a = t / 100, bb = t % 100;
      v = ab[h*10000 + abs(i - a)*100 + abs(j - bb)] * LOG2E;
    }
    if (bf32) btabf[o] = v;
    else      btab[o]  = f2bf(v);
  }
}

// ---------------------------------------------------------------------------
// 128x128 tile GEMM body (m97 structure).
// ---------------------------------------------------------------------------
template<int MODE, int BK>
__device__ __forceinline__ void gemm_body(
    const void* __restrict__ Ap, const u16* __restrict__ BT,
    const float* __restrict__ g1, const float* __restrict__ b1,
    const float* __restrict__ m1, const float* __restrict__ v1,
    void* __restrict__ o0, void* __restrict__ o1, int K, int row_base,
    int cb, int rb, u16* lds)
{
  constexpr int HALF = (BK == 64) ? 8192 : 4096;
  const int tid = threadIdx.x;
  const int lane = tid & 63, wid = tid >> 6;
  const int lg = lane >> 4, lc = lane & 15;
  const int wr = wid >> 1, wc = wid & 1;
  const int row0 = rb*128, col0 = cb*128;
  f32x4 acc[4][4] = {};
  const int nkb = K / BK;

  for (int kb = 0; kb < nkb; ++kb){
    if (MODE == 0){
      const float* A = (const float*)Ap;
      constexpr int NIT = (BK == 64) ? 8 : 4;
      constexpr int CSH = (BK == 64) ? 4 : 3;
      constexpr int CMK = (BK == 64) ? 15 : 7;
      #pragma unroll
      for (int it = 0; it < NIT; ++it){
        int lin = tid + it*256;
        int row = lin >> CSH, c4 = lin & CMK;
        const fl4 v = *(const fl4*)(A + (size_t)(row0 + row)*K + kb*BK + c4*4);
        u32x2 p;
        p[0] = pk2bf(v[0], v[1]);
        p[1] = pk2bf(v[2], v[3]);
        *(u32x2*)&lds[row*BK + c4*4] = p;
      }
    } else if (BK == 32){
      const u16* A = (const u16*)Ap;
      #pragma unroll
      for (int it = 0; it < 2; ++it){
        int lin = tid + it*256;
        int row = lin >> 2, seg = lin & 3;
        gld16(A + (size_t)(row0 + row)*K + kb*32 + seg*8, &lds[lin*8]);
      }
    } else {
      const u16* A = (const u16*)Ap;
      #pragma unroll
      for (int it = 0; it < 4; ++it){
        int lin = tid + it*256;
        int row = lin >> 3, seg = lin & 7;
        gld16(A + (size_t)(row0 + row)*K + kb*64 + seg*8, &lds[lin*8]);
      }
    }
    if (BK == 32){
      #pragma unroll
      for (int it = 0; it < 2; ++it){
        int lin = tid + it*256;
        int col = lin >> 2, seg = lin & 3;
        gld16(BT + (size_t)(col0 + col)*K + kb*32 + seg*8, &lds[HALF + lin*8]);
      }
    } else {
      #pragma unroll
      for (int it = 0; it < 4; ++it){
        int lin = tid + it*256;
        int col = lin >> 3, seg = lin & 7;
        gld16(BT + (size_t)(col0 + col)*K + kb*64 + seg*8, &lds[HALF + lin*8]);
      }
    }
    __syncthreads();
    #pragma unroll
    for (int kh = 0; kh < BK/32; ++kh){
      short8 af[4], bfr[4];
      #pragma unroll
      for (int rt = 0; rt < 4; ++rt)
        af[rt] = *(const short8*)&lds[(wr*64 + rt*16 + lc)*BK + kh*32 + lg*8];
      #pragma unroll
      for (int ct = 0; ct < 4; ++ct)
        bfr[ct] = *(const short8*)&lds[HALF + (wc*64 + ct*16 + lc)*BK + kh*32 + lg*8];
      #pragma unroll
      for (int rt = 0; rt < 4; ++rt)
        #pragma unroll
        for (int ct = 0; ct < 4; ++ct)
          acc[rt][ct] = mfma16(af[rt], bfr[ct], acc[rt][ct]);
    }
    __syncthreads();
  }

  if (MODE == 0){
    u16* qws = (u16*)o0;
    #pragma unroll
    for (int ct = 0; ct < 4; ++ct){
      int c = col0 + wc*64 + ct*16 + lc;
      float sc = g1[c] * rsqrtf(v1[c] + EPSF);
      float sh = (b1[c] - m1[c]*sc) * QSCALE;   // 0.125*log2e fold
      int h = c >> 6, dk = c & 63;
      #pragma unroll
      for (int rt = 0; rt < 4; ++rt)
        #pragma unroll
        for (int r = 0; r < 4; ++r){
          int mr = row0 + wr*64 + rt*16 + lg*4 + r;
          int b = mr >> 10, n = mr & 1023;
          qws[(size_t)((b*NH + h)*1024 + n)*64 + dk] =
              f2bf(acc[rt][ct][r]*QSCALE + sh);
        }
    }
  } else if (MODE == 1){
    u16* Kw = (u16*)o0; u16* Vw = (u16*)o1;
    #pragma unroll
    for (int ct = 0; ct < 4; ++ct){
      int c = col0 + wc*64 + ct*16 + lc;
      float sc = g1[c] * rsqrtf(v1[c] + EPSF);
      float sh = b1[c] - m1[c]*sc;
      int h = c / 320, sub = c % 320;
      #pragma unroll
      for (int rt = 0; rt < 4; ++rt)
        #pragma unroll
        for (int r = 0; r < 4; ++r){
          int t = row0 + wr*64 + rt*16 + lg*4 + r;
          if (t < NTP){
            u16 val = f2bf(acc[rt][ct][r] + sh);
            if (sub < 64){
              size_t o = ((size_t)h*13 + (t >> 5))*2048
                       + ((t >> 4) & 1)*1024 + (sub >> 5)*512
                       + ((sub >> 3) & 3)*128 + (t & 15)*8 + (sub & 7);
              Kw[o] = val;
            } else {
              int dv = sub - 64;
              size_t o = ((size_t)h*13 + (t >> 5))*8192
                       + (dv >> 6)*2048 + ((dv >> 4) & 3)*512
                       + ((t >> 3) & 3)*128 + (dv & 15)*8 + (t & 7);
              Vw[o] = val;
            }
          }
        }
    }
  } else {
    float* outp = (float*)o0;
    #pragma unroll
    for (int ct = 0; ct < 4; ++ct){
      int c = col0 + wc*64 + ct*16 + lc;
      float sc = g1[c] * rsqrtf(v1[c] + EPSF);
      float sh = b1[c] - m1[c]*sc;
      #pragma unroll
      for (int rt = 0; rt < 4; ++rt)
        #pragma unroll
        for (int r = 0; r < 4; ++r){
          int mr = row_base + row0 + wr*64 + rt*16 + lg*4 + r;
          outp[(size_t)mr*512 + c] = acc[rt][ct][r] + sh;
        }
    }
  }
}

// Fused kv-proj + q-proj
__global__ __launch_bounds__(256) void qkv_kernel(
    const float* __restrict__ x, const u16* __restrict__ qwT,
    const float* __restrict__ q_g, const float* __restrict__ q_b,
    const float* __restrict__ q_m, const float* __restrict__ q_v,
    u16* __restrict__ qws,
    const u16* __restrict__ textb, const u16* __restrict__ kvwT,
    const float* __restrict__ kv_g, const float* __restrict__ kv_b,
    const float* __restrict__ kv_m, const float* __restrict__ kv_v,
    u16* __restrict__ Kw, u16* __restrict__ Vw)
{
  __shared__ u16 lds[16384];
  const int L = blockIdx.x;
  if (L < 80){
    gemm_body<1, 32>(textb, kvwT, kv_g, kv_b, kv_m, kv_v, Kw, Vw,
                     512, 0, L % 20, L / 20, lds);
  } else {
    const int b2 = L - 80;
    const int xcd = b2 & 7, s = b2 >> 3;
    gemm_body<0, 64>(x, qwT, q_g, q_b, q_m, q_v, qws, nullptr,
                     512, 0, s % 4, xcd*32 + s/4, lds);
  }
}

// Quarter-path proj (ws-limited fallback)
template<int MODE, int NXB, int BK>
__global__ __launch_bounds__(256) void gemm_kernel(
    const void* __restrict__ Ap, const u16* __restrict__ BT,
    const float* __restrict__ g1, const float* __restrict__ b1,
    const float* __restrict__ m1, const float* __restrict__ v1,
    void* __restrict__ o0, void* __restrict__ o1, int K, int row_base,
    int rbpx)
{
  __shared__ u16 lds[BK == 64 ? 16384 : 8192];
  int cb, rb;
  if (NXB > 0){
    const int L = blockIdx.x;
    const int xcd = L & 7, s = L >> 3;
    cb = s % NXB;
    rb = xcd * rbpx + s / NXB;
  } else {
    cb = blockIdx.x; rb = blockIdx.y;
  }
  gemm_body<MODE, BK>(Ap, BT, g1, b1, m1, v1, o0, o1, K, row_base, cb, rb, lds);
}

// ---------------------------------------------------------------------------
// 8-phase 256x256 GEMM for proj (unchanged from R14)
// ---------------------------------------------------------------------------
__global__ __launch_bounds__(512, 2) void gemm256_kernel(
    const u16* __restrict__ A, const u16* __restrict__ BT,
    const float* __restrict__ g1, const float* __restrict__ b1,
    const float* __restrict__ m1, const float* __restrict__ v1,
    float* __restrict__ outp)
{
  extern __shared__ u16 lds[];     // A: [buf][half][128][64]; B at +32768
  const int tid = threadIdx.x;
  const int lane = tid & 63, wid = tid >> 6;
  const int lg = lane >> 4, lc = lane & 15;
  const int wm = wid >> 2, wn = wid & 3;

  const int L = blockIdx.x;        // 256 blocks: xcd owns 16 row-blocks
  const int xcd = L & 7, s = L >> 3;
  const int cb = s & 1, rb = xcd*16 + (s >> 1);
  const int row0 = rb*256, col0 = cb*256;

  const int r0s = tid >> 3,  s0 = tid & 7;
  const int r1s = (512 + tid) >> 3, s1 = (512 + tid) & 7;
  const int ss0 = s0 ^ ((r0s & 4) >> 1);
  const int ss1 = s1 ^ ((r1s & 4) >> 1);
  const size_t aoff0 = (size_t)(row0 + r0s)*2048 + ss0*8;
  const size_t aoff1 = (size_t)(row0 + r1s)*2048 + ss1*8;
  const size_t boff0 = (size_t)(col0 + r0s)*2048 + ss0*8;
  const size_t boff1 = (size_t)(col0 + r1s)*2048 + ss1*8;
  const int d0 = tid*8, d1 = 4096 + tid*8;     // u16 dst within half

  auto stage = [&](int tk, int ht){
    const int bb = (tk & 1) * 16384;
    if (ht < 2){
      gld16(A + aoff0 + (size_t)ht*262144 + tk*64, &lds[bb + ht*8192 + d0]);
      gld16(A + aoff1 + (size_t)ht*262144 + tk*64, &lds[bb + ht*8192 + d1]);
    } else {
      const int h2 = ht - 2;
      gld16(BT + boff0 + (size_t)h2*262144 + tk*64, &lds[32768 + bb + h2*8192 + d0]);
      gld16(BT + boff1 + (size_t)h2*262144 + tk*64, &lds[32768 + bb + h2*8192 + d1]);
    }
  };

  const int lgx = (lg*8) ^ ((lc & 4) << 2);
  const int abase = wm*8192 + lc*64 + lgx;               // + fr*1024 + kh*32
  const int bbase = 32768 + (wn >> 1)*8192 + ((wn & 1)*64 + lc)*64 + lgx;

  f32x4 acc[8][4] = {};
  short8 bf[4][2];

  stage(0, 0); stage(0, 1); stage(0, 2); stage(0, 3);
  asm volatile("s_waitcnt vmcnt(0)" ::: "memory");
  __builtin_amdgcn_s_barrier();

  for (int tk = 0; tk < 32; ++tk){
    const int bc = (tk & 1) * 16384;
    #pragma unroll
    for (int p = 0; p < 4; ++p){
      if (p == 0){
        #pragma unroll
        for (int cn = 0; cn < 4; ++cn){
          bf[cn][0] = *(const short8*)&lds[bbase + bc + cn*1024];
          bf[cn][1] = *(const short8*)&lds[bbase + bc + cn*1024 + 32];
        }
      }
      short8 af[2][2];
      #pragma unroll
      for (int j = 0; j < 2; ++j){
        af[j][0] = *(const short8*)&lds[abase + bc + (2*p + j)*1024];
        af[j][1] = *(const short8*)&lds[abase + bc + (2*p + j)*1024 + 32];
      }
      if (tk < 31) stage(tk + 1, p);
      if (p == 3) asm volatile("s_waitcnt vmcnt(0)" ::: "memory");
      __builtin_amdgcn_s_barrier();
      __builtin_amdgcn_s_setprio(1);
      #pragma unroll
      for (int j = 0; j < 2; ++j)
        #pragma unroll
        for (int cn = 0; cn < 4; ++cn){
          acc[2*p + j][cn] = mfma16(af[j][0], bf[cn][0], acc[2*p + j][cn]);
          acc[2*p + j][cn] = mfma16(af[j][1], bf[cn][1], acc[2*p + j][cn]);
        }
      __builtin_amdgcn_s_setprio(0);
    }
  }

  #pragma unroll
  for (int cn = 0; cn < 4; ++cn){
    const int c = col0 + wn*64 + cn*16 + lc;
    const float sc = g1[c] * rsqrtf(v1[c] + EPSF);
    const float sh = b1[c] - m1[c]*sc;
    #pragma unroll
    for (int fr = 0; fr < 8; ++fr)
      #pragma unroll
      for (int r = 0; r < 4; ++r){
        const int mr = row0 + wm*128 + fr*16 + lg*4 + r;
        outp[(size_t)mr*512 + c] = acc[fr][cn][r] + sh;
      }
  }
}

// ---------------------------------------------------------------------------
// Flash attention. BF32: bias table is fp32 (direct f32x4 C-init, no unpack)
// ---------------------------------------------------------------------------
template<int BF32>
__global__ __launch_bounds__(256, 4) void attn_kernel(
    const u16* __restrict__ qws, const u16* __restrict__ Kw,
    const u16* __restrict__ Vw, const void* __restrict__ btab_,
    u16* __restrict__ aws, int b_base, int bzbits)
{
  __shared__ char Pb[2][64*80];     // P bf16 [64 q][32 t], row stride 80 B
  __shared__ float lsum[64];

  const int tid = threadIdx.x;
  const int lane = tid & 63, wid = tid >> 6;
  const int lg = lane >> 4, lc = lane & 15;

  const int L = blockIdx.x;
  const int slot = L >> 3;
  const int bz = slot & ((1 << bzbits) - 1);
  const int qt = slot >> bzbits;            // 0..15
  const int h = L & 7;                      // one head per XCD
  const int b = b_base + bz, n0 = qt*64;

  const u16* qp = qws + ((size_t)((b*NH + h)*1024 + n0 + wid*16 + lc))*64 + lg*8;
  const short8 qf0 = *(const short8*)qp;
  const short8 qf1 = *(const short8*)(qp + 32);

  const u16* kbase = Kw + (size_t)h*13*2048 + lg*128 + lc*8;
  const u16* vbase = Vw + (size_t)h*13*8192 + wid*2048 + lg*128 + lc*8;
  const size_t bofs = ((size_t)(h*16 + qt)*13)*2048 + wid*512 + lg*64 + lc*4;
  const u16*   btb  = (const u16*)btab_ + bofs;
  const float* btbf = (const float*)btab_ + bofs;

  float lpart = 0.f;
  f32x4 acc[4][4] = {};
  char* pwr = &Pb[0][0] + (wid*16 + lc)*80 + lg*8;   // + buf*5120 + tt*32

  #pragma unroll
  for (int c = 0; c < 13; ++c){
    const int s = c & 1;
    const u16* vc = vbase + (size_t)c*8192;
    short8 vf0 = *(const short8*)(vc);
    short8 vf1 = *(const short8*)(vc + 512);
    short8 vf2 = *(const short8*)(vc + 1024);
    short8 vf3 = *(const short8*)(vc + 1536);
    const u16* kc = kbase + (size_t)c*2048;
    #pragma unroll
    for (int tt = 0; tt < 2; ++tt){
      short8 kf0 = *(const short8*)(kc + tt*1024);
      short8 kf1 = *(const short8*)(kc + tt*1024 + 512);
      f32x4 sv;
      if (BF32){
        sv = *(const f32x4*)(btbf + c*2048 + tt*256);
      } else {
        u32x2 bw = *(const u32x2*)(btb + c*2048 + tt*256);
        sv[0] = u2f(bw[0] << 16); sv[1] = u2f(bw[0] & 0xffff0000u);
        sv[2] = u2f(bw[1] << 16); sv[3] = u2f(bw[1] & 0xffff0000u);
      }
      sv = mfma16(kf0, qf0, sv);
      sv = mfma16(kf1, qf1, sv);
      float p0 = __builtin_exp2f(sv[0]);
      float p1 = __builtin_exp2f(sv[1]);
      float p2 = __builtin_exp2f(sv[2]);
      float p3 = __builtin_exp2f(sv[3]);
      lpart += (p0 + p1) + (p2 + p3);
      u32x2 pw;
      pw[0] = pk2bf(p0, p1);
      pw[1] = pk2bf(p2, p3);
      *(u32x2*)(pwr + s*5120 + tt*32) = pw;
    }
    __syncthreads();                                  // Pb[s] ready for all
    const char* pb = &Pb[s][0];
    short8 pa[4];
    #pragma unroll
    for (int rt = 0; rt < 4; ++rt)
      pa[rt] = *(const short8*)(pb + (rt*16 + lc)*80 + lg*16);
    __builtin_amdgcn_s_setprio(1);
    #pragma unroll
    for (int rt = 0; rt < 4; ++rt){
      acc[rt][0] = mfma16(pa[rt], vf0, acc[rt][0]);
      acc[rt][1] = mfma16(pa[rt], vf1, acc[rt][1]);
      acc[rt][2] = mfma16(pa[rt], vf2, acc[rt][2]);
      acc[rt][3] = mfma16(pa[rt], vf3, acc[rt][3]);
    }
    __builtin_amdgcn_s_setprio(0);
  }

  lpart += __shfl_xor(lpart, 16);
  lpart += __shfl_xor(lpart, 32);
  if (lane < 16) lsum[wid*16 + lane] = lpart;
  __syncthreads();

  #pragma unroll
  for (int rt = 0; rt < 4; ++rt){
    #pragma unroll
    for (int r = 0; r < 4; ++r){
      const int qrow = rt*16 + lg*4 + r;
      const float linv = __builtin_amdgcn_rcpf(lsum[qrow]);
      const size_t obase = ((size_t)(bz*1024 + n0 + qrow))*2048 + h*256;
      #pragma unroll
      for (int ct = 0; ct < 4; ++ct){
        float x = acc[rt][ct][r] * linv;
        float x2 = x * x;
        float z = x * __builtin_fmaf(0.0356774081f, x2, 0.7978845608f);
        float e = __builtin_exp2f(z * (2.0f * LOG2E));
        float rr = __builtin_amdgcn_rcpf(1.0f + e);
        float g = __builtin_fmaf(-x, rr, x);
        aws[obase + wid*64 + ct*16 + lc] = f2bf(g);
      }
    }
  }
}

// ---------------------------------------------------------------------------
extern "C" void kernel_launch(void* const* d_in, const int* in_sizes, int n_in,
                              void* d_out, int out_size, void* d_ws, size_t ws_size,
                              hipStream_t stream)
{
  (void)in_sizes; (void)n_in; (void)out_size;
  const float* x    = (const float*)d_in[0];
  const float* text = (const float*)d_in[1];
  const float* q_w  = (const float*)d_in[2];
  const float* q_g  = (const float*)d_in[3];
  const float* q_b  = (const float*)d_in[4];
  const float* q_m  = (const float*)d_in[5];
  const float* q_v  = (const float*)d_in[6];
  const float* kv_w = (const float*)d_in[7];
  const float* kv_g = (const float*)d_in[8];
  const float* kv_b = (const float*)d_in[9];
  const float* kv_m = (const float*)d_in[10];
  const float* kv_v = (const float*)d_in[11];
  const float* p_w  = (const float*)d_in[12];
  const float* p_g  = (const float*)d_in[13];
  const float* p_b  = (const float*)d_in[14];
  const float* p_m  = (const float*)d_in[15];
  const float* p_v  = (const float*)d_in[16];
  const float* ab   = (const float*)d_in[17];
  float* out = (float*)d_out;

  char* ws = (char*)d_ws;
  u16* qwT   = (u16*)(ws + 0);            //  512x512   [N][K]
  u16* kvwT  = (u16*)(ws + 524288);       // 2560x512   [N][K]
  u16* pwT   = (u16*)(ws + 3145728);      //  512x2048  [N][K]
  u16* textb = (u16*)(ws + 5242880);      //  512x512
  u16* btab  = (u16*)(ws + 5767168);      //  8x16x13x2048 bf16 (frag-tiled)
  u16* Kw    = (u16*)(ws + 12582912);     //  8x13x2048 (frag-tiled)
  u16* Vw    = (u16*)(ws + 13008896);     //  8x13x8192 (frag-tiled)
  u16* qws   = (u16*)(ws + 14712832);     //  32x8x1024x64
  u16* aws   = (u16*)(ws + 48267264);     //  32768x2048 (full) or 8192x2048
  float* btabf = (float*)(ws + 182484992);//  8x16x13x2048 fp32 (if room)

  const bool full = ws_size >= (size_t)182484992ull;
  const bool bf32 = ws_size >= (size_t)WS_BF32;

  hipFuncSetAttribute((const void*)gemm256_kernel,
                      hipFuncAttributeMaxDynamicSharedMemorySize, 131072);

  // fused prep: wconv x3 + textconv + bias
  prep_kernel<<<14976, 256, 0, stream>>>(
      q_w, q_g, q_v, qwT, kv_w, kv_g, kv_v, kvwT,
      p_w, p_g, p_v, pwT, text, textb, ab, btab, btabf, bf32 ? 1 : 0);

  // fused kv-proj + q-proj (kv's 80 blocks hide under q's 1024)
  qkv_kernel<<<1104, 256, 0, stream>>>(
      x, qwT, q_g, q_b, q_m, q_v, qws,
      textb, kvwT, kv_g, kv_b, kv_m, kv_v, Kw, Vw);

  if (full){
    if (bf32)
      attn_kernel<1><<<4096, 256, 0, stream>>>(qws, Kw, Vw, btabf, aws, 0, 5);
    else
      attn_kernel<0><<<4096, 256, 0, stream>>>(qws, Kw, Vw, btab, aws, 0, 5);
    gemm256_kernel<<<256, 512, 131072, stream>>>(
        aws, pwT, p_g, p_b, p_m, p_v, out);
  } else {
    for (int q = 0; q < 4; ++q){
      attn_kernel<0><<<1024, 256, 0, stream>>>(qws, Kw, Vw, btab, aws, q*8, 3);
      gemm_kernel<2, 4, 64><<<256, 256, 0, stream>>>(
          aws, pwT, p_g, p_b, p_m, p_v, out, nullptr, 2048, q*8192, 8);
    }
  }
}

// Round 19
// 260.998 us; speedup vs baseline: 1.0067x; 1.0067x over previous
//
#include <hip/hip_runtime.h>
#include <hip/hip_bf16.h>

// ---------------------------------------------------------------------------
// Attention_81449759801699 on MI355X (gfx950)
// R19 = R17 exactly (proven best, 261.6 us), rebuilt single-variant:
// fp32-bias template removed (rule #19: co-compiled variants perturb
// codegen). Fused prep; fused kv+q proj; bf16-bias 4-wave attn; 8-phase
// 256x256 proj.
// ---------------------------------------------------------------------------

typedef unsigned short u16;
typedef unsigned int u32;
typedef float  f32x4  __attribute__((ext_vector_type(4)));
typedef float  fl4    __attribute__((ext_vector_type(4)));
typedef short  short8 __attribute__((ext_vector_type(8)));
typedef u32    u32x4  __attribute__((ext_vector_type(4)));
typedef u32    u32x2  __attribute__((ext_vector_type(2)));

#define EPSF 1e-5f
#define NH 8
#define NTP 416                        // 400 text tokens padded to 416 (13*32)
#define LOG2E 1.4426950408889634f
#define QSCALE (0.125f * LOG2E)

static __device__ __forceinline__ u16 f2bf(float f){
  u32 u = __builtin_bit_cast(u32, f);
  u += 0x7FFFu + ((u >> 16) & 1u);     // RNE (finite inputs only)
  return (u16)(u >> 16);
}
static __device__ __forceinline__ float u2f(u32 u){
  return __builtin_bit_cast(float, u);
}
static __device__ __forceinline__ u32 pk2bf(float lo, float hi){
  float2 f; f.x = lo; f.y = hi;
  __hip_bfloat162 b = __float22bfloat162_rn(f);
  u32 l = (u32)__bfloat16_as_ushort(b.x);
  u32 h = (u32)__bfloat16_as_ushort(b.y);
  return l | (h << 16);
}
static __device__ __forceinline__ f32x4 mfma16(short8 a, short8 b, f32x4 c){
  return __builtin_amdgcn_mfma_f32_16x16x32_bf16(a, b, c, 0, 0, 0);
}
static __device__ __forceinline__ void gld16(const void* g, void* l){
  __builtin_amdgcn_global_load_lds(
      (const __attribute__((address_space(1))) u32*)g,
      (__attribute__((address_space(3))) u32*)l, 16, 0, 0);
}

// ---------------------------------------------------------------------------
// Fused prep: flat grid, 256 thr.
//  [0,64):    wconv q_w   (8x8,  R=512,  C=512)  -> qwT
//  [64,384):  wconv kv_w  (40x8, R=512,  C=2560) -> kvwT
//  [384,640): wconv p_w   (8x32, R=2048, C=512)  -> pwT
//  [640,1664):   text -> bf16 padded to 512 rows -> textb
//  [1664,14976): bias table, OUTPUT-linear (coalesced writes), x log2e
// ---------------------------------------------------------------------------
__device__ __forceinline__ void wconv_body(
    const float* __restrict__ w, const float* __restrict__ gamma,
    const float* __restrict__ var, u16* __restrict__ wT,
    int R, int C, int tx, int ty, int tid, u16* tile)
{
  #pragma unroll
  for (int i = 0; i < 16; ++i){
    int lin = tid + i*256;
    int rr = lin >> 6, cc = lin & 63;
    int c = tx*64 + cc;
    float s = gamma[c] * rsqrtf(var[c] + EPSF);
    tile[rr*65 + cc] = f2bf(w[(size_t)(ty*64 + rr)*C + c] * s);
  }
  __syncthreads();
  #pragma unroll
  for (int i = 0; i < 16; ++i){
    int lin = tid + i*256;
    int cc = lin >> 6, rr = lin & 63;
    wT[(size_t)(tx*64 + cc)*R + ty*64 + rr] = tile[rr*65 + cc];
  }
}

__global__ __launch_bounds__(256) void prep_kernel(
    const float* __restrict__ q_w, const float* __restrict__ q_g,
    const float* __restrict__ q_v, u16* __restrict__ qwT,
    const float* __restrict__ kv_w, const float* __restrict__ kv_g,
    const float* __restrict__ kv_v, u16* __restrict__ kvwT,
    const float* __restrict__ p_w, const float* __restrict__ p_g,
    const float* __restrict__ p_v, u16* __restrict__ pwT,
    const float* __restrict__ text, u16* __restrict__ textb,
    const float* __restrict__ ab, u16* __restrict__ btab)
{
  __shared__ u16 tile[64*65];
  const int bk = blockIdx.x, tid = threadIdx.x;
  if (bk < 64){
    wconv_body(q_w, q_g, q_v, qwT, 512, 512, bk & 7, bk >> 3, tid, tile);
  } else if (bk < 384){
    int bb = bk - 64;
    wconv_body(kv_w, kv_g, kv_v, kvwT, 512, 2560, bb % 40, bb / 40, tid, tile);
  } else if (bk < 640){
    int bb = bk - 384;
    wconv_body(p_w, p_g, p_v, pwT, 2048, 512, bb & 7, bb >> 3, tid, tile);
  } else if (bk < 1664){
    int idx = (bk - 640)*256 + tid;       // 512*512
    int r = idx >> 9, c = idx & 511;
    float v = (r < 400) ? text[r*512 + c] : 0.f;
    textb[idx] = f2bf(v);
  } else {
    // bias, output-linear: o -> (h,n,t); btab write fully coalesced
    int o = (bk - 1664)*256 + tid;        // 8*16*13*2048
    int tl  = o & 3;
    int nl  = (o >> 2) & 15;
    int lgq = (o >> 6) & 3;
    int tt  = (o >> 8) & 1;
    int w   = (o >> 9) & 3;
    int tile_ = o >> 11;
    int c   = tile_ % 13;
    int hq  = tile_ / 13;
    int qt  = hq & 15, h = hq >> 4;
    int t = c*32 + tt*16 + lgq*4 + tl;
    int n = qt*64 + w*16 + nl;
    float v;
    if (t >= 400) v = -1e30f;
    else {
      int i = n >> 5, j = n & 31;
      int a = t / 100, bb = t % 100;
      v = ab[h*10000 + abs(i - a)*100 + abs(j - bb)] * LOG2E;
    }
    btab[o] = f2bf(v);
  }
}

// ---------------------------------------------------------------------------
// 128x128 tile GEMM body (m97 structure).
// MODE 0: A=x fp32 (cvt_pk reg-stage) -> q_ws[b][h][n][64] bf16, *QSCALE
// MODE 1: A=text_bf -> K/V fragment-tiled (t<416 guard)
// MODE 2: A=a_ws bf16 -> d_out fp32 (+BN shift), rows offset row_base
// ---------------------------------------------------------------------------
template<int MODE, int BK>
__device__ __forceinline__ void gemm_body(
    const void* __restrict__ Ap, const u16* __restrict__ BT,
    const float* __restrict__ g1, const float* __restrict__ b1,
    const float* __restrict__ m1, const float* __restrict__ v1,
    void* __restrict__ o0, void* __restrict__ o1, int K, int row_base,
    int cb, int rb, u16* lds)
{
  constexpr int HALF = (BK == 64) ? 8192 : 4096;
  const int tid = threadIdx.x;
  const int lane = tid & 63, wid = tid >> 6;
  const int lg = lane >> 4, lc = lane & 15;
  const int wr = wid >> 1, wc = wid & 1;
  const int row0 = rb*128, col0 = cb*128;
  f32x4 acc[4][4] = {};
  const int nkb = K / BK;

  for (int kb = 0; kb < nkb; ++kb){
    if (MODE == 0){
      const float* A = (const float*)Ap;
      constexpr int NIT = (BK == 64) ? 8 : 4;
      constexpr int CSH = (BK == 64) ? 4 : 3;
      constexpr int CMK = (BK == 64) ? 15 : 7;
      #pragma unroll
      for (int it = 0; it < NIT; ++it){
        int lin = tid + it*256;
        int row = lin >> CSH, c4 = lin & CMK;
        const fl4 v = *(const fl4*)(A + (size_t)(row0 + row)*K + kb*BK + c4*4);
        u32x2 p;
        p[0] = pk2bf(v[0], v[1]);
        p[1] = pk2bf(v[2], v[3]);
        *(u32x2*)&lds[row*BK + c4*4] = p;
      }
    } else if (BK == 32){
      const u16* A = (const u16*)Ap;
      #pragma unroll
      for (int it = 0; it < 2; ++it){
        int lin = tid + it*256;
        int row = lin >> 2, seg = lin & 3;
        gld16(A + (size_t)(row0 + row)*K + kb*32 + seg*8, &lds[lin*8]);
      }
    } else {
      const u16* A = (const u16*)Ap;
      #pragma unroll
      for (int it = 0; it < 4; ++it){
        int lin = tid + it*256;
        int row = lin >> 3, seg = lin & 7;
        gld16(A + (size_t)(row0 + row)*K + kb*64 + seg*8, &lds[lin*8]);
      }
    }
    if (BK == 32){
      #pragma unroll
      for (int it = 0; it < 2; ++it){
        int lin = tid + it*256;
        int col = lin >> 2, seg = lin & 3;
        gld16(BT + (size_t)(col0 + col)*K + kb*32 + seg*8, &lds[HALF + lin*8]);
      }
    } else {
      #pragma unroll
      for (int it = 0; it < 4; ++it){
        int lin = tid + it*256;
        int col = lin >> 3, seg = lin & 7;
        gld16(BT + (size_t)(col0 + col)*K + kb*64 + seg*8, &lds[HALF + lin*8]);
      }
    }
    __syncthreads();
    #pragma unroll
    for (int kh = 0; kh < BK/32; ++kh){
      short8 af[4], bfr[4];
      #pragma unroll
      for (int rt = 0; rt < 4; ++rt)
        af[rt] = *(const short8*)&lds[(wr*64 + rt*16 + lc)*BK + kh*32 + lg*8];
      #pragma unroll
      for (int ct = 0; ct < 4; ++ct)
        bfr[ct] = *(const short8*)&lds[HALF + (wc*64 + ct*16 + lc)*BK + kh*32 + lg*8];
      #pragma unroll
      for (int rt = 0; rt < 4; ++rt)
        #pragma unroll
        for (int ct = 0; ct < 4; ++ct)
          acc[rt][ct] = mfma16(af[rt], bfr[ct], acc[rt][ct]);
    }
    __syncthreads();
  }

  if (MODE == 0){
    u16* qws = (u16*)o0;
    #pragma unroll
    for (int ct = 0; ct < 4; ++ct){
      int c = col0 + wc*64 + ct*16 + lc;
      float sc = g1[c] * rsqrtf(v1[c] + EPSF);
      float sh = (b1[c] - m1[c]*sc) * QSCALE;   // 0.125*log2e fold
      int h = c >> 6, dk = c & 63;
      #pragma unroll
      for (int rt = 0; rt < 4; ++rt)
        #pragma unroll
        for (int r = 0; r < 4; ++r){
          int mr = row0 + wr*64 + rt*16 + lg*4 + r;
          int b = mr >> 10, n = mr & 1023;
          qws[(size_t)((b*NH + h)*1024 + n)*64 + dk] =
              f2bf(acc[rt][ct][r]*QSCALE + sh);
        }
    }
  } else if (MODE == 1){
    u16* Kw = (u16*)o0; u16* Vw = (u16*)o1;
    #pragma unroll
    for (int ct = 0; ct < 4; ++ct){
      int c = col0 + wc*64 + ct*16 + lc;
      float sc = g1[c] * rsqrtf(v1[c] + EPSF);
      float sh = b1[c] - m1[c]*sc;
      int h = c / 320, sub = c % 320;
      #pragma unroll
      for (int rt = 0; rt < 4; ++rt)
        #pragma unroll
        for (int r = 0; r < 4; ++r){
          int t = row0 + wr*64 + rt*16 + lg*4 + r;
          if (t < NTP){
            u16 val = f2bf(acc[rt][ct][r] + sh);
            if (sub < 64){
              size_t o = ((size_t)h*13 + (t >> 5))*2048
                       + ((t >> 4) & 1)*1024 + (sub >> 5)*512
                       + ((sub >> 3) & 3)*128 + (t & 15)*8 + (sub & 7);
              Kw[o] = val;
            } else {
              int dv = sub - 64;
              size_t o = ((size_t)h*13 + (t >> 5))*8192
                       + (dv >> 6)*2048 + ((dv >> 4) & 3)*512
                       + ((t >> 3) & 3)*128 + (dv & 15)*8 + (t & 7);
              Vw[o] = val;
            }
          }
        }
    }
  } else {
    float* outp = (float*)o0;
    #pragma unroll
    for (int ct = 0; ct < 4; ++ct){
      int c = col0 + wc*64 + ct*16 + lc;
      float sc = g1[c] * rsqrtf(v1[c] + EPSF);
      float sh = b1[c] - m1[c]*sc;
      #pragma unroll
      for (int rt = 0; rt < 4; ++rt)
        #pragma unroll
        for (int r = 0; r < 4; ++r){
          int mr = row_base + row0 + wr*64 + rt*16 + lg*4 + r;
          outp[(size_t)mr*512 + c] = acc[rt][ct][r] + sh;
        }
    }
  }
}

// Fused kv-proj + q-proj: blocks [0,80) kv (MODE1 BK32, 20x4); [80,1104)
// q-proj (MODE0 BK64, XCD-chunked; 80%8==0 preserves L&7 mapping).
__global__ __launch_bounds__(256) void qkv_kernel(
    const float* __restrict__ x, const u16* __restrict__ qwT,
    const float* __restrict__ q_g, const float* __restrict__ q_b,
    const float* __restrict__ q_m, const float* __restrict__ q_v,
    u16* __restrict__ qws,
    const u16* __restrict__ textb, const u16* __restrict__ kvwT,
    const float* __restrict__ kv_g, const float* __restrict__ kv_b,
    const float* __restrict__ kv_m, const float* __restrict__ kv_v,
    u16* __restrict__ Kw, u16* __restrict__ Vw)
{
  __shared__ u16 lds[16384];
  const int L = blockIdx.x;
  if (L < 80){
    gemm_body<1, 32>(textb, kvwT, kv_g, kv_b, kv_m, kv_v, Kw, Vw,
                     512, 0, L % 20, L / 20, lds);
  } else {
    const int b2 = L - 80;
    const int xcd = b2 & 7, s = b2 >> 3;
    gemm_body<0, 64>(x, qwT, q_g, q_b, q_m, q_v, qws, nullptr,
                     512, 0, s % 4, xcd*32 + s/4, lds);
  }
}

// Quarter-path proj (ws-limited fallback)
template<int MODE, int NXB, int BK>
__global__ __launch_bounds__(256) void gemm_kernel(
    const void* __restrict__ Ap, const u16* __restrict__ BT,
    const float* __restrict__ g1, const float* __restrict__ b1,
    const float* __restrict__ m1, const float* __restrict__ v1,
    void* __restrict__ o0, void* __restrict__ o1, int K, int row_base,
    int rbpx)
{
  __shared__ u16 lds[BK == 64 ? 16384 : 8192];
  int cb, rb;
  if (NXB > 0){
    const int L = blockIdx.x;
    const int xcd = L & 7, s = L >> 3;
    cb = s % NXB;
    rb = xcd * rbpx + s / NXB;
  } else {
    cb = blockIdx.x; rb = blockIdx.y;
  }
  gemm_body<MODE, BK>(Ap, BT, g1, b1, m1, v1, o0, o1, K, row_base, cb, rb, lds);
}

// ---------------------------------------------------------------------------
// 8-phase 256x256 GEMM for proj (unchanged from R14)
// ---------------------------------------------------------------------------
__global__ __launch_bounds__(512, 2) void gemm256_kernel(
    const u16* __restrict__ A, const u16* __restrict__ BT,
    const float* __restrict__ g1, const float* __restrict__ b1,
    const float* __restrict__ m1, const float* __restrict__ v1,
    float* __restrict__ outp)
{
  extern __shared__ u16 lds[];     // A: [buf][half][128][64]; B at +32768
  const int tid = threadIdx.x;
  const int lane = tid & 63, wid = tid >> 6;
  const int lg = lane >> 4, lc = lane & 15;
  const int wm = wid >> 2, wn = wid & 3;

  const int L = blockIdx.x;        // 256 blocks: xcd owns 16 row-blocks
  const int xcd = L & 7, s = L >> 3;
  const int cb = s & 1, rb = xcd*16 + (s >> 1);
  const int row0 = rb*256, col0 = cb*256;

  const int r0s = tid >> 3,  s0 = tid & 7;
  const int r1s = (512 + tid) >> 3, s1 = (512 + tid) & 7;
  const int ss0 = s0 ^ ((r0s & 4) >> 1);
  const int ss1 = s1 ^ ((r1s & 4) >> 1);
  const size_t aoff0 = (size_t)(row0 + r0s)*2048 + ss0*8;
  const size_t aoff1 = (size_t)(row0 + r1s)*2048 + ss1*8;
  const size_t boff0 = (size_t)(col0 + r0s)*2048 + ss0*8;
  const size_t boff1 = (size_t)(col0 + r1s)*2048 + ss1*8;
  const int d0 = tid*8, d1 = 4096 + tid*8;     // u16 dst within half

  auto stage = [&](int tk, int ht){
    const int bb = (tk & 1) * 16384;
    if (ht < 2){
      gld16(A + aoff0 + (size_t)ht*262144 + tk*64, &lds[bb + ht*8192 + d0]);
      gld16(A + aoff1 + (size_t)ht*262144 + tk*64, &lds[bb + ht*8192 + d1]);
    } else {
      const int h2 = ht - 2;
      gld16(BT + boff0 + (size_t)h2*262144 + tk*64, &lds[32768 + bb + h2*8192 + d0]);
      gld16(BT + boff1 + (size_t)h2*262144 + tk*64, &lds[32768 + bb + h2*8192 + d1]);
    }
  };

  const int lgx = (lg*8) ^ ((lc & 4) << 2);
  const int abase = wm*8192 + lc*64 + lgx;               // + fr*1024 + kh*32
  const int bbase = 32768 + (wn >> 1)*8192 + ((wn & 1)*64 + lc)*64 + lgx;

  f32x4 acc[8][4] = {};
  short8 bf[4][2];

  stage(0, 0); stage(0, 1); stage(0, 2); stage(0, 3);
  asm volatile("s_waitcnt vmcnt(0)" ::: "memory");
  __builtin_amdgcn_s_barrier();

  for (int tk = 0; tk < 32; ++tk){
    const int bc = (tk & 1) * 16384;
    #pragma unroll
    for (int p = 0; p < 4; ++p){
      if (p == 0){
        #pragma unroll
        for (int cn = 0; cn < 4; ++cn){
          bf[cn][0] = *(const short8*)&lds[bbase + bc + cn*1024];
          bf[cn][1] = *(const short8*)&lds[bbase + bc + cn*1024 + 32];
        }
      }
      short8 af[2][2];
      #pragma unroll
      for (int j = 0; j < 2; ++j){
        af[j][0] = *(const short8*)&lds[abase + bc + (2*p + j)*1024];
        af[j][1] = *(const short8*)&lds[abase + bc + (2*p + j)*1024 + 32];
      }
      if (tk < 31) stage(tk + 1, p);
      if (p == 3) asm volatile("s_waitcnt vmcnt(0)" ::: "memory");
      __builtin_amdgcn_s_barrier();
      __builtin_amdgcn_s_setprio(1);
      #pragma unroll
      for (int j = 0; j < 2; ++j)
        #pragma unroll
        for (int cn = 0; cn < 4; ++cn){
          acc[2*p + j][cn] = mfma16(af[j][0], bf[cn][0], acc[2*p + j][cn]);
          acc[2*p + j][cn] = mfma16(af[j][1], bf[cn][1], acc[2*p + j][cn]);
        }
      __builtin_amdgcn_s_setprio(0);
    }
  }

  #pragma unroll
  for (int cn = 0; cn < 4; ++cn){
    const int c = col0 + wn*64 + cn*16 + lc;
    const float sc = g1[c] * rsqrtf(v1[c] + EPSF);
    const float sh = b1[c] - m1[c]*sc;
    #pragma unroll
    for (int fr = 0; fr < 8; ++fr)
      #pragma unroll
      for (int r = 0; r < 4; ++r){
        const int mr = row0 + wm*128 + fr*16 + lg*4 + r;
        outp[(size_t)mr*512 + c] = acc[fr][cn][r] + sh;
      }
  }
}

// ---------------------------------------------------------------------------
// Flash attention (R17 proven config: bf16 bias, 4 waves/SIMD, VGPR 64)
// ---------------------------------------------------------------------------
__global__ __launch_bounds__(256, 4) void attn_kernel(
    const u16* __restrict__ qws, const u16* __restrict__ Kw,
    const u16* __restrict__ Vw, const u16* __restrict__ btab,
    u16* __restrict__ aws, int b_base, int bzbits)
{
  __shared__ char Pb[2][64*80];     // P bf16 [64 q][32 t], row stride 80 B
  __shared__ float lsum[64];

  const int tid = threadIdx.x;
  const int lane = tid & 63, wid = tid >> 6;
  const int lg = lane >> 4, lc = lane & 15;

  const int L = blockIdx.x;
  const int slot = L >> 3;
  const int bz = slot & ((1 << bzbits) - 1);
  const int qt = slot >> bzbits;            // 0..15
  const int h = L & 7;                      // one head per XCD
  const int b = b_base + bz, n0 = qt*64;

  const u16* qp = qws + ((size_t)((b*NH + h)*1024 + n0 + wid*16 + lc))*64 + lg*8;
  const short8 qf0 = *(const short8*)qp;
  const short8 qf1 = *(const short8*)(qp + 32);

  const u16* kbase = Kw + (size_t)h*13*2048 + lg*128 + lc*8;
  const u16* vbase = Vw + (size_t)h*13*8192 + wid*2048 + lg*128 + lc*8;
  const u16* btb   = btab + ((size_t)(h*16 + qt)*13)*2048 + wid*512 + lg*64 + lc*4;

  float lpart = 0.f;
  f32x4 acc[4][4] = {};
  char* pwr = &Pb[0][0] + (wid*16 + lc)*80 + lg*8;   // + buf*5120 + tt*32

  #pragma unroll
  for (int c = 0; c < 13; ++c){
    const int s = c & 1;
    const u16* vc = vbase + (size_t)c*8192;
    short8 vf0 = *(const short8*)(vc);
    short8 vf1 = *(const short8*)(vc + 512);
    short8 vf2 = *(const short8*)(vc + 1024);
    short8 vf3 = *(const short8*)(vc + 1536);
    const u16* kc = kbase + (size_t)c*2048;
    const u16* bc = btb + (size_t)c*2048;
    #pragma unroll
    for (int tt = 0; tt < 2; ++tt){
      short8 kf0 = *(const short8*)(kc + tt*1024);
      short8 kf1 = *(const short8*)(kc + tt*1024 + 512);
      u32x2 bw = *(const u32x2*)(bc + tt*256);
      f32x4 sv;
      sv[0] = u2f(bw[0] << 16); sv[1] = u2f(bw[0] & 0xffff0000u);
      sv[2] = u2f(bw[1] << 16); sv[3] = u2f(bw[1] & 0xffff0000u);
      sv = mfma16(kf0, qf0, sv);
      sv = mfma16(kf1, qf1, sv);
      float p0 = __builtin_exp2f(sv[0]);
      float p1 = __builtin_exp2f(sv[1]);
      float p2 = __builtin_exp2f(sv[2]);
      float p3 = __builtin_exp2f(sv[3]);
      lpart += (p0 + p1) + (p2 + p3);
      u32x2 pw;
      pw[0] = pk2bf(p0, p1);
      pw[1] = pk2bf(p2, p3);
      *(u32x2*)(pwr + s*5120 + tt*32) = pw;
    }
    __syncthreads();                                  // Pb[s] ready for all
    const char* pb = &Pb[s][0];
    short8 pa[4];
    #pragma unroll
    for (int rt = 0; rt < 4; ++rt)
      pa[rt] = *(const short8*)(pb + (rt*16 + lc)*80 + lg*16);
    __builtin_amdgcn_s_setprio(1);
    #pragma unroll
    for (int rt = 0; rt < 4; ++rt){
      acc[rt][0] = mfma16(pa[rt], vf0, acc[rt][0]);
      acc[rt][1] = mfma16(pa[rt], vf1, acc[rt][1]);
      acc[rt][2] = mfma16(pa[rt], vf2, acc[rt][2]);
      acc[rt][3] = mfma16(pa[rt], vf3, acc[rt][3]);
    }
    __builtin_amdgcn_s_setprio(0);
  }

  lpart += __shfl_xor(lpart, 16);
  lpart += __shfl_xor(lpart, 32);
  if (lane < 16) lsum[wid*16 + lane] = lpart;
  __syncthreads();

  #pragma unroll
  for (int rt = 0; rt < 4; ++rt){
    #pragma unroll
    for (int r = 0; r < 4; ++r){
      const int qrow = rt*16 + lg*4 + r;
      const float linv = __builtin_amdgcn_rcpf(lsum[qrow]);
      const size_t obase = ((size_t)(bz*1024 + n0 + qrow))*2048 + h*256;
      #pragma unroll
      for (int ct = 0; ct < 4; ++ct){
        float x = acc[rt][ct][r] * linv;
        float x2 = x * x;
        float z = x * __builtin_fmaf(0.0356774081f, x2, 0.7978845608f);
        float e = __builtin_exp2f(z * (2.0f * LOG2E));
        float rr = __builtin_amdgcn_rcpf(1.0f + e);
        float g = __builtin_fmaf(-x, rr, x);
        aws[obase + wid*64 + ct*16 + lc] = f2bf(g);
      }
    }
  }
}

// ---------------------------------------------------------------------------
extern "C" void kernel_launch(void* const* d_in, const int* in_sizes, int n_in,
                              void* d_out, int out_size, void* d_ws, size_t ws_size,
                              hipStream_t stream)
{
  (void)in_sizes; (void)n_in; (void)out_size;
  const float* x    = (const float*)d_in[0];
  const float* text = (const float*)d_in[1];
  const float* q_w  = (const float*)d_in[2];
  const float* q_g  = (const float*)d_in[3];
  const float* q_b  = (const float*)d_in[4];
  const float* q_m  = (const float*)d_in[5];
  const float* q_v  = (const float*)d_in[6];
  const float* kv_w = (const float*)d_in[7];
  const float* kv_g = (const float*)d_in[8];
  const float* kv_b = (const float*)d_in[9];
  const float* kv_m = (const float*)d_in[10];
  const float* kv_v = (const float*)d_in[11];
  const float* p_w  = (const float*)d_in[12];
  const float* p_g  = (const float*)d_in[13];
  const float* p_b  = (const float*)d_in[14];
  const float* p_m  = (const float*)d_in[15];
  const float* p_v  = (const float*)d_in[16];
  const float* ab   = (const float*)d_in[17];
  float* out = (float*)d_out;

  char* ws = (char*)d_ws;
  u16* qwT   = (u16*)(ws + 0);            //  512x512   [N][K]
  u16* kvwT  = (u16*)(ws + 524288);       // 2560x512   [N][K]
  u16* pwT   = (u16*)(ws + 3145728);      //  512x2048  [N][K]
  u16* textb = (u16*)(ws + 5242880);      //  512x512
  u16* btab  = (u16*)(ws + 5767168);      //  8x16x13x2048 (frag-tiled, x log2e)
  u16* Kw    = (u16*)(ws + 12582912);     //  8x13x2048 (frag-tiled)
  u16* Vw    = (u16*)(ws + 13008896);     //  8x13x8192 (frag-tiled)
  u16* qws   = (u16*)(ws + 14712832);     //  32x8x1024x64
  u16* aws   = (u16*)(ws + 48267264);     //  32768x2048 (full) or 8192x2048

  const bool full = ws_size >= (size_t)182484992ull;

  hipFuncSetAttribute((const void*)gemm256_kernel,
                      hipFuncAttributeMaxDynamicSharedMemorySize, 131072);

  // fused prep: wconv x3 + textconv + bias
  prep_kernel<<<14976, 256, 0, stream>>>(
      q_w, q_g, q_v, qwT, kv_w, kv_g, kv_v, kvwT,
      p_w, p_g, p_v, pwT, text, textb, ab, btab);

  // fused kv-proj + q-proj (kv's 80 blocks hide under q's 1024)
  qkv_kernel<<<1104, 256, 0, stream>>>(
      x, qwT, q_g, q_b, q_m, q_v, qws,
      textb, kvwT, kv_g, kv_b, kv_m, kv_v, Kw, Vw);

  if (full){
    // flat 4096 blocks: h=L&7, slot=L>>3: bz=slot&31, qt=slot>>5
    attn_kernel<<<4096, 256, 0, stream>>>(qws, Kw, Vw, btab, aws, 0, 5);
    // proj: M=32768 N=512 K=2048 — 8-phase 256x256, 256 blocks x 512 thr
    gemm256_kernel<<<256, 512, 131072, stream>>>(
        aws, pwT, p_g, p_b, p_m, p_v, out);
  } else {
    for (int q = 0; q < 4; ++q){
      attn_kernel<<<1024, 256, 0, stream>>>(qws, Kw, Vw, btab, aws, q*8, 3);
      gemm_kernel<2, 4, 64><<<256, 256, 0, stream>>>(
          aws, pwT, p_g, p_b, p_m, p_v, out, nullptr, 2048, q*8192, 8);
    }
  }
}